// Round 4
// baseline (725.887 us; speedup 1.0000x reference)
//
#include <hip/hip_runtime.h>
#include <hip/hip_cooperative_groups.h>
#include <hip/hip_bf16.h>
#include <stdint.h>
#include <stddef.h>

namespace cg = cooperative_groups;

#define RNUM   3
#define NNODES 50000
#define ENUM   1000000
#define BATCH  2048
#define INP    256
#define HID    512
#define OUTC   256
#define BN_EPS 1e-5f
#define NBLK   256

typedef __bf16 bf16x8 __attribute__((ext_vector_type(8)));
typedef float  f32x4  __attribute__((ext_vector_type(4)));

__device__ inline unsigned short f2bf(float f) {
    union { float f; unsigned u; } c; c.f = f;
    unsigned u = c.u;
    return (unsigned short)((u + 0x7fffu + ((u >> 16) & 1u)) >> 16);  // RNE
}

__device__ inline uint4 pack8(float4 a, float4 b) {
    uint4 r;
    r.x = (unsigned)f2bf(a.x) | ((unsigned)f2bf(a.y) << 16);
    r.y = (unsigned)f2bf(a.z) | ((unsigned)f2bf(a.w) << 16);
    r.z = (unsigned)f2bf(b.x) | ((unsigned)f2bf(b.y) << 16);
    r.w = (unsigned)f2bf(b.z) | ((unsigned)f2bf(b.w) << 16);
    return r;
}

// LDS union:
//  wt   : float T[32][33]                          (4224 B)
//  scan : int rank[2048] | float degs[2048] | int wsum[4]   (16400 B)
//  gemm : ushort As[64][40] | ushort Bs[64][40] | float gs[512] | float ss[512] (14336 B)
#define SMEM_BYTES 16512

__global__ __launch_bounds__(256) void k_mega(
    const float* __restrict__ features, const float* __restrict__ W1,
    const float* __restrict__ b1, const float* __restrict__ W2,
    const float* __restrict__ b2, const float* __restrict__ gamma,
    const float* __restrict__ beta, const int* __restrict__ edge_index,
    const int* __restrict__ bn, float* __restrict__ out,
    int* __restrict__ inv, int* __restrict__ appear, int* __restrict__ kcount,
    float* __restrict__ deg, float* __restrict__ musum, float* __restrict__ sqsum,
    unsigned short* __restrict__ W1T, unsigned short* __restrict__ W2T,
    int2* __restrict__ edges, float* __restrict__ xw,
    float* __restrict__ hbase, float* __restrict__ yw)
{
    cg::grid_group grid = cg::this_grid();
    __shared__ __align__(16) char smem[SMEM_BYTES];
    const int bid = blockIdx.x, tid = threadIdx.x;
    const int gid = bid * 256 + tid;

    // ================= P0: weight transpose + inv + zeros =================
    {
        float (*T)[33] = (float (*)[33])smem;
        int z = bid >> 7, rem = bid & 127;
        const float* W = z ? W2 : W1;
        unsigned short* WT = z ? W2T : W1T;
        int K = z ? HID : INP, N = z ? OUTC : HID;
        int kt = z ? (rem >> 3) : (rem >> 4);
        int nt = z ? (rem & 7) : (rem & 15);
        int tx = tid & 31, ty = tid >> 5;
#pragma unroll
        for (int j = 0; j < 4; ++j)
            T[ty + j * 8][tx] = W[(size_t)(kt * 32 + ty + j * 8) * N + nt * 32 + tx];
        __syncthreads();
#pragma unroll
        for (int j = 0; j < 4; ++j)
            WT[(size_t)(nt * 32 + ty + j * 8) * K + kt * 32 + tx] = f2bf(T[tx][ty + j * 8]);
    }
    if (gid < NNODES) {
        int lo = 0, hi = BATCH;
        while (lo < hi) { int mid = (lo + hi) >> 1; if (bn[mid] < gid) lo = mid + 1; else hi = mid; }
        inv[gid] = (lo < BATCH && bn[lo] == gid) ? lo : -1;
    }
    if (gid < RNUM * BATCH) appear[gid] = 0;
    if (gid < RNUM * HID)   { musum[gid] = 0.0f; sqsum[gid] = 0.0f; }
    if (gid < RNUM)         kcount[gid] = 0;
    __threadfence();
    grid.sync();

    // ================= P1: edge mask + compact =================
    for (int z = 0; z < RNUM; ++z) {
        const int* src = edge_index + (size_t)z * 2 * ENUM;
        const int* dst = src + ENUM;
        int2* ed = edges + (size_t)z * ENUM;
        int* app = appear + z * BATCH;
        for (int e4 = gid; e4 < ENUM / 4; e4 += NBLK * 256) {
            int4 s4 = ((const int4*)src)[e4];
            int4 d4 = ((const int4*)dst)[e4];
            int ss4[4] = {s4.x, s4.y, s4.z, s4.w};
            int dd4[4] = {d4.x, d4.y, d4.z, d4.w};
#pragma unroll
            for (int i = 0; i < 4; ++i) {
                int ps = inv[ss4[i]];
                int pd = inv[dd4[i]];
                if (ps >= 0 && pd >= 0) {
                    int idx = atomicAdd(kcount + z, 1);
                    ed[idx] = make_int2(ps, pd);
                    app[ps] = 1;
                    app[pd] = 1;
                }
            }
        }
    }
    __threadfence();
    grid.sync();

    // ================= P2: rank scan + edge remap + degree (blocks 0..2) ==
    if (bid < RNUM) {
        int* rnk = (int*)smem;                 // 2048 ints
        float* degs = (float*)(smem + 8192);   // 2048 floats
        int* wsum = (int*)(smem + 16384);      // 4 ints
        int z = bid;
        const int* ap = appear + z * BATCH;
        int2* ed = edges + (size_t)z * ENUM;
        float* dg = deg + z * BATCH;
        // chunked scan: thread t owns [8t, 8t+8)
        int v[8], s = 0, base = tid * 8;
#pragma unroll
        for (int j = 0; j < 8; ++j) { v[j] = ap[base + j]; s += v[j]; }
        int lane = tid & 63, w = tid >> 6;
        int x = s;
#pragma unroll
        for (int off = 1; off < 64; off <<= 1) {
            int y = __shfl_up(x, off, 64);
            if (lane >= off) x += y;
        }
        if (lane == 63) wsum[w] = x;
        degs[tid] = 0.0f; degs[tid + 256] = 0.0f; degs[tid + 512] = 0.0f; degs[tid + 768] = 0.0f;
        degs[tid + 1024] = 0.0f; degs[tid + 1280] = 0.0f; degs[tid + 1536] = 0.0f; degs[tid + 1792] = 0.0f;
        __syncthreads();
        int woff = 0;
#pragma unroll
        for (int k = 0; k < 4; ++k) if (k < w) woff += wsum[k];
        int run = woff + x - s;                 // exclusive prefix of this chunk
#pragma unroll
        for (int j = 0; j < 8; ++j) { run += v[j]; rnk[base + j] = run - 1; }
        __syncthreads();
        int K = kcount[z];
        for (int e = tid; e < K; e += 256) {
            int2 E = ed[e];
            int ss2 = rnk[E.x], dd2 = rnk[E.y];
            ed[e] = make_int2(ss2, dd2);
            atomicAdd(&degs[dd2], 1.0f);
        }
        __syncthreads();
        for (int i = tid; i < BATCH; i += 256) dg[i] = degs[i];
    }
    __threadfence();
    grid.sync();

    // ================= P3: GEMM1 (768 tiles, 3 per block) =================
    {
        unsigned short (*As)[40] = (unsigned short (*)[40])smem;
        unsigned short (*Bs)[40] = (unsigned short (*)[40])(smem + 5120);
        int lane = tid & 63, wave = tid >> 6;
        int wm = (wave & 1) * 32, wn = (wave >> 1) * 32;
        int ml = lane & 15, quad = lane >> 4, q8 = quad * 8;
        int ar = tid >> 2, aq = tid & 3;
        for (int tile = bid; tile < 768; tile += NBLK) {
            int z = tile >> 8, rem = tile & 255;
            int m0 = (rem >> 3) * 64, n0 = (rem & 7) * 64;
            const float* feat = features + (size_t)z * NNODES * INP;
            const float* dgz = deg + z * BATCH;
            float* xwz = xw + (size_t)z * BATCH * HID;
            float* hbz = hbase + (size_t)z * BATCH * HID;
            int grow = bn[m0 + ar];
            const float* aptr = feat + (size_t)grow * INP + aq * 8;
            const unsigned short* bptr = W1T + (size_t)(n0 + ar) * INP + aq * 8;
            f32x4 acc[2][2] = {};
            for (int k0 = 0; k0 < INP; k0 += 32) {
                float4 a0 = *(const float4*)(aptr + k0);
                float4 a1 = *(const float4*)(aptr + k0 + 4);
                uint4 bv = *(const uint4*)(bptr + k0);
                *(uint4*)&As[ar][aq * 8] = pack8(a0, a1);
                *(uint4*)&Bs[ar][aq * 8] = bv;
                __syncthreads();
                bf16x8 af[2], bfr[2];
#pragma unroll
                for (int mi = 0; mi < 2; ++mi) af[mi]  = *(const bf16x8*)&As[wm + mi * 16 + ml][q8];
#pragma unroll
                for (int ni = 0; ni < 2; ++ni) bfr[ni] = *(const bf16x8*)&Bs[wn + ni * 16 + ml][q8];
#pragma unroll
                for (int mi = 0; mi < 2; ++mi)
#pragma unroll
                    for (int ni = 0; ni < 2; ++ni)
                        acc[mi][ni] = __builtin_amdgcn_mfma_f32_16x16x32_bf16(af[mi], bfr[ni], acc[mi][ni], 0, 0, 0);
                __syncthreads();
            }
#pragma unroll
            for (int mi = 0; mi < 2; ++mi)
#pragma unroll
                for (int r = 0; r < 4; ++r) {
                    int row = m0 + wm + mi * 16 + quad * 4 + r;
                    float d2 = 1.0f / (dgz[row] + 1.0f);
#pragma unroll
                    for (int ni = 0; ni < 2; ++ni) {
                        int col = n0 + wn + ni * 16 + ml;
                        float c = acc[mi][ni][r];
                        xwz[(size_t)row * HID + col] = c;
                        hbz[(size_t)row * HID + col] = d2 * c + b1[col];
                    }
                }
        }
    }
    __threadfence();
    grid.sync();

    // ================= P4: edge aggregation (hid) =================
    for (int z = 0; z < RNUM; ++z) {
        int K = kcount[z];
        const int2* ed = edges + (size_t)z * ENUM;
        const float* dgz = deg + z * BATCH;
        const float* sm = xw + (size_t)z * BATCH * HID;
        float* dm = hbase + (size_t)z * BATCH * HID;
        for (int e = bid; e < K; e += NBLK) {
            int2 E = ed[e];
            float w = rsqrtf(dgz[E.x] + 1.0f) * rsqrtf(dgz[E.y] + 1.0f);
            const float* srow = sm + (size_t)E.x * HID;
            float* drow = dm + (size_t)E.y * HID;
            for (int c = tid; c < HID; c += 256)
                atomicAdd(&drow[c], w * srow[c]);
        }
    }
    __threadfence();
    grid.sync();

    // ================= P5: BN stats (192 block-tasks) =================
    if (bid < 192) {
        int z = bid >> 6;
        int r0 = (bid & 63) * 32;
        const float* h = hbase + (size_t)z * BATCH * HID;
        int c0 = tid;
        float s1a = 0, s2a = 0, s1b = 0, s2b = 0;
        for (int rr = 0; rr < 32; ++rr) {
            const float* row = h + (size_t)(r0 + rr) * HID;
            float va = row[c0];
            float vb = row[c0 + 256];
            s1a += va; s2a += va * va;
            s1b += vb; s2b += vb * vb;
        }
        atomicAdd(&musum[z * HID + c0], s1a);       atomicAdd(&sqsum[z * HID + c0], s2a);
        atomicAdd(&musum[z * HID + c0 + 256], s1b); atomicAdd(&sqsum[z * HID + c0 + 256], s2b);
    }
    __threadfence();
    grid.sync();

    // ================= P6: GEMM2 with BN fused (384 tiles) =================
    {
        unsigned short (*As)[40] = (unsigned short (*)[40])smem;
        unsigned short (*Bs)[40] = (unsigned short (*)[40])(smem + 5120);
        float* gs = (float*)(smem + 10240);
        float* ss_ = (float*)(smem + 12288);
        int lane = tid & 63, wave = tid >> 6;
        int wm = (wave & 1) * 32, wn = (wave >> 1) * 32;
        int ml = lane & 15, quad = lane >> 4, q8 = quad * 8;
        int ar = tid >> 2, aq = tid & 3;
        for (int tile = bid; tile < 384; tile += NBLK) {
            int z = tile >> 7, rem = tile & 127;
            int m0 = (rem >> 2) * 64, n0 = (rem & 3) * 64;
            const float* hz = hbase + (size_t)z * BATCH * HID;
            const float* dgz = deg + z * BATCH;
            float* ywz = yw + (size_t)z * BATCH * OUTC;
            float* oz = out + (size_t)z * BATCH * OUTC;
#pragma unroll
            for (int c = tid; c < HID; c += 256) {
                float mu = musum[z * HID + c] * (1.0f / BATCH);
                float ex2 = sqsum[z * HID + c] * (1.0f / BATCH);
                float var = ex2 - mu * mu;
                float g = rsqrtf(var + BN_EPS) * gamma[c];
                gs[c] = g;
                ss_[c] = beta[c] - mu * g;
            }
            __syncthreads();
            const float* aptr = hz + (size_t)(m0 + ar) * HID + aq * 8;
            const unsigned short* bptr = W2T + (size_t)(n0 + ar) * HID + aq * 8;
            f32x4 acc[2][2] = {};
            for (int k0 = 0; k0 < HID; k0 += 32) {
                float4 h0 = *(const float4*)(aptr + k0);
                float4 h1 = *(const float4*)(aptr + k0 + 4);
                float4 g0 = *(const float4*)(gs + k0 + aq * 8);
                float4 g1 = *(const float4*)(gs + k0 + aq * 8 + 4);
                float4 s0 = *(const float4*)(ss_ + k0 + aq * 8);
                float4 s1 = *(const float4*)(ss_ + k0 + aq * 8 + 4);
                float4 a0 = make_float4(h0.x * g0.x + s0.x, h0.y * g0.y + s0.y,
                                        h0.z * g0.z + s0.z, h0.w * g0.w + s0.w);
                float4 a1 = make_float4(h1.x * g1.x + s1.x, h1.y * g1.y + s1.y,
                                        h1.z * g1.z + s1.z, h1.w * g1.w + s1.w);
                uint4 bv = *(const uint4*)(bptr + k0);
                *(uint4*)&As[ar][aq * 8] = pack8(a0, a1);
                *(uint4*)&Bs[ar][aq * 8] = bv;
                __syncthreads();
                bf16x8 af[2], bfr[2];
#pragma unroll
                for (int mi = 0; mi < 2; ++mi) af[mi]  = *(const bf16x8*)&As[wm + mi * 16 + ml][q8];
#pragma unroll
                for (int ni = 0; ni < 2; ++ni) bfr[ni] = *(const bf16x8*)&Bs[wn + ni * 16 + ml][q8];
#pragma unroll
                for (int mi = 0; mi < 2; ++mi)
#pragma unroll
                    for (int ni = 0; ni < 2; ++ni)
                        acc[mi][ni] = __builtin_amdgcn_mfma_f32_16x16x32_bf16(af[mi], bfr[ni], acc[mi][ni], 0, 0, 0);
                __syncthreads();
            }
#pragma unroll
            for (int mi = 0; mi < 2; ++mi)
#pragma unroll
                for (int r = 0; r < 4; ++r) {
                    int row = m0 + wm + mi * 16 + quad * 4 + r;
                    float d2 = 1.0f / (dgz[row] + 1.0f);
#pragma unroll
                    for (int ni = 0; ni < 2; ++ni) {
                        int col = n0 + wn + ni * 16 + ml;
                        float c = acc[mi][ni][r];
                        ywz[(size_t)row * OUTC + col] = c;
                        oz[(size_t)row * OUTC + col] = d2 * c + b2[col];
                    }
                }
        }
    }
    __threadfence();
    grid.sync();

    // ================= P7: edge aggregation (out) =================
    for (int z = 0; z < RNUM; ++z) {
        int K = kcount[z];
        const int2* ed = edges + (size_t)z * ENUM;
        const float* dgz = deg + z * BATCH;
        const float* sm = yw + (size_t)z * BATCH * OUTC;
        float* dm = out + (size_t)z * BATCH * OUTC;
        for (int e = bid; e < K; e += NBLK) {
            int2 E = ed[e];
            float w = rsqrtf(dgz[E.x] + 1.0f) * rsqrtf(dgz[E.y] + 1.0f);
            const float* srow = sm + (size_t)E.x * OUTC;
            float* drow = dm + (size_t)E.y * OUTC;
            for (int c = tid; c < OUTC; c += 256)
                atomicAdd(&drow[c], w * srow[c]);
        }
    }
}

// ---------------- launch ----------------
extern "C" void kernel_launch(void* const* d_in, const int* in_sizes, int n_in,
                              void* d_out, int out_size, void* d_ws, size_t ws_size,
                              hipStream_t stream) {
    const float* features    = (const float*)d_in[0];
    const float* W1          = (const float*)d_in[1];
    const float* b1          = (const float*)d_in[2];
    const float* W2          = (const float*)d_in[3];
    const float* b2          = (const float*)d_in[4];
    const float* gamma       = (const float*)d_in[5];
    const float* beta        = (const float*)d_in[6];
    const int*   edge_index  = (const int*)d_in[7];
    const int*   batch_nodes = (const int*)d_in[8];
    float* out = (float*)d_out;

    char* p = (char*)d_ws;
    size_t cur = 0;
    auto alloc = [&](size_t bytes) {
        void* r = p + cur;
        cur = (cur + bytes + 255) & ~(size_t)255;
        return r;
    };
    int*   inv    = (int*)  alloc(NNODES * sizeof(int));
    int*   appear = (int*)  alloc(RNUM * BATCH * sizeof(int));
    int*   kcount = (int*)  alloc(RNUM * sizeof(int));
    float* deg    = (float*)alloc(RNUM * BATCH * sizeof(float));
    float* musum  = (float*)alloc(RNUM * HID * sizeof(float));
    float* sqsum  = (float*)alloc(RNUM * HID * sizeof(float));
    unsigned short* W1T = (unsigned short*)alloc((size_t)HID * INP * sizeof(unsigned short));
    unsigned short* W2T = (unsigned short*)alloc((size_t)OUTC * HID * sizeof(unsigned short));
    int2*  edges  = (int2*) alloc((size_t)RNUM * ENUM * sizeof(int2));
    float* xw     = (float*)alloc((size_t)RNUM * BATCH * HID * sizeof(float));
    float* hbase  = (float*)alloc((size_t)RNUM * BATCH * HID * sizeof(float));
    float* yw     = (float*)alloc((size_t)RNUM * BATCH * OUTC * sizeof(float));
    (void)ws_size; (void)in_sizes; (void)n_in; (void)out_size;

    void* args[] = {
        (void*)&features, (void*)&W1, (void*)&b1, (void*)&W2, (void*)&b2,
        (void*)&gamma, (void*)&beta, (void*)&edge_index, (void*)&batch_nodes,
        (void*)&out, (void*)&inv, (void*)&appear, (void*)&kcount, (void*)&deg,
        (void*)&musum, (void*)&sqsum, (void*)&W1T, (void*)&W2T, (void*)&edges,
        (void*)&xw, (void*)&hbase, (void*)&yw
    };
    hipLaunchCooperativeKernel((const void*)k_mega, dim3(NBLK), dim3(256),
                               args, 0, stream);
}

// Round 5
// 401.046 us; speedup vs baseline: 1.8100x; 1.8100x over previous
//
#include <hip/hip_runtime.h>
#include <hip/hip_bf16.h>
#include <stdint.h>
#include <stddef.h>

#define RNUM   3
#define NNODES 50000
#define ENUM   1000000
#define BATCH  2048
#define INP    256
#define HID    512
#define OUTC   256
#define BN_EPS 1e-5f

typedef __bf16 bf16x8 __attribute__((ext_vector_type(8)));
typedef float  f32x4  __attribute__((ext_vector_type(4)));

__device__ inline unsigned short f2bf(float f) {
    union { float f; unsigned u; } c; c.f = f;
    unsigned u = c.u;
    return (unsigned short)((u + 0x7fffu + ((u >> 16) & 1u)) >> 16);  // RNE
}

__device__ inline uint4 pack8(float4 a, float4 b) {
    uint4 r;
    r.x = (unsigned)f2bf(a.x) | ((unsigned)f2bf(a.y) << 16);
    r.y = (unsigned)f2bf(a.z) | ((unsigned)f2bf(a.w) << 16);
    r.z = (unsigned)f2bf(b.x) | ((unsigned)f2bf(b.y) << 16);
    r.w = (unsigned)f2bf(b.z) | ((unsigned)f2bf(b.w) << 16);
    return r;
}

// ========== K1: prep — weight transpose(bf16), inv (binary search), zeroing ==========
__global__ __launch_bounds__(256) void k_prep(
    const float* __restrict__ W1, const float* __restrict__ W2,
    const int* __restrict__ bn,
    unsigned short* __restrict__ W1T, unsigned short* __restrict__ W2T,
    int* __restrict__ inv, int* __restrict__ appear, int* __restrict__ kcount,
    float* __restrict__ musum, float* __restrict__ sqsum,
    float* __restrict__ xa, float* __restrict__ ha) {
    __shared__ float T[32][33];
    const int bid = blockIdx.x, tid = threadIdx.x;
    const int gid = bid * 256 + tid;
    const int nth = gridDim.x * 256;

    if (bid < 256) {  // weight transpose tiles: W1 8x16=128, W2 16x8=128
        int z = bid >> 7, rem = bid & 127;
        const float* W = z ? W2 : W1;
        unsigned short* WT = z ? W2T : W1T;
        int K = z ? HID : INP, N = z ? OUTC : HID;
        int kt = z ? (rem >> 3) : (rem >> 4);
        int nt = z ? (rem & 7) : (rem & 15);
        int tx = tid & 31, ty = tid >> 5;
#pragma unroll
        for (int j = 0; j < 4; ++j)
            T[ty + j * 8][tx] = W[(size_t)(kt * 32 + ty + j * 8) * N + nt * 32 + tx];
        __syncthreads();
#pragma unroll
        for (int j = 0; j < 4; ++j)
            WT[(size_t)(nt * 32 + ty + j * 8) * K + kt * 32 + tx] = f2bf(T[tx][ty + j * 8]);
    }
    if (gid < NNODES) {
        int lo = 0, hi = BATCH;
        while (lo < hi) { int mid = (lo + hi) >> 1; if (bn[mid] < gid) lo = mid + 1; else hi = mid; }
        inv[gid] = (lo < BATCH && bn[lo] == gid) ? lo : -1;
    }
    float4 z4 = make_float4(0.f, 0.f, 0.f, 0.f);
    const int XA4 = RNUM * BATCH * INP / 4;
    const int HA4 = RNUM * BATCH * HID / 4;
    for (int i = gid; i < XA4; i += nth) ((float4*)xa)[i] = z4;
    for (int i = gid; i < HA4; i += nth) ((float4*)ha)[i] = z4;
    if (gid < RNUM * BATCH) appear[gid] = 0;
    if (gid < RNUM * HID) { musum[gid] = 0.0f; sqsum[gid] = 0.0f; }
    if (gid < RNUM) kcount[gid] = 0;
}

// ========== K2: edge mask + compact ==========
__global__ void k_mask(const int* __restrict__ edge_index, const int* __restrict__ inv,
                       int* __restrict__ appear, int2* __restrict__ edges,
                       int* __restrict__ kcount) {
    int z = blockIdx.z;
    const int* src = edge_index + (size_t)z * 2 * ENUM;
    const int* dst = src + ENUM;
    int2* ed = edges + (size_t)z * ENUM;
    int* app = appear + z * BATCH;
    int stride = gridDim.x * blockDim.x;
    for (int e4 = blockIdx.x * blockDim.x + threadIdx.x; e4 < ENUM / 4; e4 += stride) {
        int4 s4 = ((const int4*)src)[e4];
        int4 d4 = ((const int4*)dst)[e4];
        int ss[4] = {s4.x, s4.y, s4.z, s4.w};
        int dd[4] = {d4.x, d4.y, d4.z, d4.w};
#pragma unroll
        for (int i = 0; i < 4; ++i) {
            int ps = inv[ss[i]];
            int pd = inv[dd[i]];
            if (ps >= 0 && pd >= 0) {
                int idx = atomicAdd(kcount + z, 1);
                ed[idx] = make_int2(ps, pd);
                app[ps] = 1;
                app[pd] = 1;
            }
        }
    }
}

// ========== K3: rank scan + edge remap + degree + c-vector ==========
__global__ __launch_bounds__(1024) void k_scanDeg(const int* __restrict__ appear,
                                                  int2* __restrict__ edges,
                                                  const int* __restrict__ kcount,
                                                  float* __restrict__ deg,
                                                  float* __restrict__ cvec) {
    __shared__ int buf[2][BATCH];
    __shared__ float degs[BATCH];
    __shared__ float cs[BATCH];
    int z = blockIdx.x;
    const int* ap = appear + z * BATCH;
    int2* ed = edges + (size_t)z * ENUM;
    float* dg = deg + z * BATCH;
    float* cv = cvec + z * BATCH;
    int t = threadIdx.x;
    buf[0][t] = ap[t];
    buf[0][t + 1024] = ap[t + 1024];
    degs[t] = 0.0f; degs[t + 1024] = 0.0f;
    cs[t] = 0.0f; cs[t + 1024] = 0.0f;
    __syncthreads();
    int cur = 0;
    for (int off = 1; off < BATCH; off <<= 1) {
        int nxt = cur ^ 1;
        int i1 = t, i2 = t + 1024;
        buf[nxt][i1] = buf[cur][i1] + (i1 >= off ? buf[cur][i1 - off] : 0);
        buf[nxt][i2] = buf[cur][i2] + (i2 >= off ? buf[cur][i2 - off] : 0);
        __syncthreads();
        cur = nxt;
    }
    int K = kcount[z];
    for (int e = t; e < K; e += 1024) {
        int2 E = ed[e];
        int s = buf[cur][E.x] - 1;
        int d = buf[cur][E.y] - 1;
        ed[e] = make_int2(s, d);
        atomicAdd(&degs[d], 1.0f);
    }
    __threadfence_block();
    __syncthreads();
    for (int e = t; e < K; e += 1024) {
        int2 E = ed[e];  // now rank-indexed
        atomicAdd(&cs[E.y], rsqrtf(degs[E.x] + 1.0f) * rsqrtf(degs[E.y] + 1.0f));
    }
    __syncthreads();
    dg[t] = degs[t];
    dg[t + 1024] = degs[t + 1024];
    cv[t] = cs[t] + 1.0f / (degs[t] + 1.0f);
    cv[t + 1024] = cs[t + 1024] + 1.0f / (degs[t + 1024] + 1.0f);
}

// ========== K4: xa += norm * x[s]  (edge-only aggregation of gathered features) =====
__global__ void k_aggx(const int2* __restrict__ edges, const int* __restrict__ kcount,
                       const float* __restrict__ deg, const float* __restrict__ features,
                       const int* __restrict__ bn, float* __restrict__ xa) {
    int z = blockIdx.z;
    int K = kcount[z];
    const int2* ed = edges + (size_t)z * ENUM;
    const float* dgz = deg + z * BATCH;
    const float* feat = features + (size_t)z * NNODES * INP;
    float* xaz = xa + (size_t)z * BATCH * INP;
    int slot = threadIdx.x >> 6, lane = threadIdx.x & 63;  // 4 edges/block, 64 lanes x f4
    for (int e = blockIdx.x * 4 + slot; e < K; e += gridDim.x * 4) {
        int2 E = ed[e];
        float w = rsqrtf(dgz[E.x] + 1.0f) * rsqrtf(dgz[E.y] + 1.0f);
        const float4* srow = (const float4*)(feat + (size_t)bn[E.x] * INP);
        float* drow = xaz + (size_t)E.y * INP;
        float4 v = srow[lane];
        atomicAdd(&drow[lane * 4 + 0], w * v.x);
        atomicAdd(&drow[lane * 4 + 1], w * v.y);
        atomicAdd(&drow[lane * 4 + 2], w * v.z);
        atomicAdd(&drow[lane * 4 + 3], w * v.w);
    }
}

// ========== K5: GEMM1  h = (xa + dinv^2 * x) @ W1 + b1 ; fused BN column stats ======
__global__ __launch_bounds__(256) void k_gemm1(
    const float* __restrict__ features, const int* __restrict__ bn,
    const float* __restrict__ xa, const unsigned short* __restrict__ W1T,
    const float* __restrict__ b1, const float* __restrict__ deg,
    float* __restrict__ h, float* __restrict__ musum, float* __restrict__ sqsum) {
    __shared__ __align__(16) unsigned short As[64][40];
    __shared__ __align__(16) unsigned short Bs[64][40];
    int z = blockIdx.z;
    const float* feat = features + (size_t)z * NNODES * INP;
    const float* xaz = xa + (size_t)z * BATCH * INP;
    const float* dgz = deg + z * BATCH;
    float* hz = h + (size_t)z * BATCH * HID;
    int m0 = blockIdx.y * 64, n0 = blockIdx.x * 64;
    int t = threadIdx.x;
    int ar = t >> 2, aq = t & 3;
    int grow = bn[m0 + ar];
    const float* fptr = feat + (size_t)grow * INP + aq * 8;
    const float* xptr = xaz + (size_t)(m0 + ar) * INP + aq * 8;
    float d2row = 1.0f / (dgz[m0 + ar] + 1.0f);
    const unsigned short* bptr = W1T + (size_t)(n0 + ar) * INP + aq * 8;

    int lane = t & 63, wave = t >> 6;
    int wm = (wave & 1) * 32, wn = (wave >> 1) * 32;
    int ml = lane & 15, quad = lane >> 4, q8 = quad * 8;

    f32x4 acc[2][2] = {};
    for (int k0 = 0; k0 < INP; k0 += 32) {
        float4 f0 = *(const float4*)(fptr + k0);
        float4 f1 = *(const float4*)(fptr + k0 + 4);
        float4 x0 = *(const float4*)(xptr + k0);
        float4 x1 = *(const float4*)(xptr + k0 + 4);
        float4 a0 = make_float4(x0.x + d2row * f0.x, x0.y + d2row * f0.y,
                                x0.z + d2row * f0.z, x0.w + d2row * f0.w);
        float4 a1 = make_float4(x1.x + d2row * f1.x, x1.y + d2row * f1.y,
                                x1.z + d2row * f1.z, x1.w + d2row * f1.w);
        uint4 bv = *(const uint4*)(bptr + k0);
        *(uint4*)&As[ar][aq * 8] = pack8(a0, a1);
        *(uint4*)&Bs[ar][aq * 8] = bv;
        __syncthreads();
        bf16x8 af[2], bfr[2];
#pragma unroll
        for (int mi = 0; mi < 2; ++mi) af[mi]  = *(const bf16x8*)&As[wm + mi * 16 + ml][q8];
#pragma unroll
        for (int ni = 0; ni < 2; ++ni) bfr[ni] = *(const bf16x8*)&Bs[wn + ni * 16 + ml][q8];
#pragma unroll
        for (int mi = 0; mi < 2; ++mi)
#pragma unroll
            for (int ni = 0; ni < 2; ++ni)
                acc[mi][ni] = __builtin_amdgcn_mfma_f32_16x16x32_bf16(af[mi], bfr[ni], acc[mi][ni], 0, 0, 0);
        __syncthreads();
    }
    // epilogue: h = acc + b1 ; BN partial sums (wave-reduced over 32 rows, then atomics)
#pragma unroll
    for (int ni = 0; ni < 2; ++ni) {
        int col = n0 + wn + ni * 16 + ml;
        float bcol = b1[col];
        float p1 = 0.0f, p2 = 0.0f;
#pragma unroll
        for (int mi = 0; mi < 2; ++mi)
#pragma unroll
            for (int r = 0; r < 4; ++r) {
                int row = m0 + wm + mi * 16 + quad * 4 + r;
                float c = acc[mi][ni][r] + bcol;
                hz[(size_t)row * HID + col] = c;
                p1 += c; p2 += c * c;
            }
        p1 += __shfl_xor(p1, 32); p1 += __shfl_xor(p1, 16);
        p2 += __shfl_xor(p2, 32); p2 += __shfl_xor(p2, 16);
        if (quad == 0) {
            atomicAdd(&musum[z * HID + col], p1);
            atomicAdd(&sqsum[z * HID + col], p2);
        }
    }
}

// ========== K6: ha += norm * h[s]  (edge-only aggregation of hidden) ==========
__global__ void k_aggh(const int2* __restrict__ edges, const int* __restrict__ kcount,
                       const float* __restrict__ deg, const float* __restrict__ h,
                       float* __restrict__ ha) {
    int z = blockIdx.z;
    int K = kcount[z];
    const int2* ed = edges + (size_t)z * ENUM;
    const float* dgz = deg + z * BATCH;
    const float* hz = h + (size_t)z * BATCH * HID;
    float* haz = ha + (size_t)z * BATCH * HID;
    int slot = threadIdx.x >> 7, lane = threadIdx.x & 127;  // 2 edges/block, 128 lanes x f4
    for (int e = blockIdx.x * 2 + slot; e < K; e += gridDim.x * 2) {
        int2 E = ed[e];
        float w = rsqrtf(dgz[E.x] + 1.0f) * rsqrtf(dgz[E.y] + 1.0f);
        const float4* srow = (const float4*)(hz + (size_t)E.x * HID);
        float* drow = haz + (size_t)E.y * HID;
        float4 v = srow[lane];
        atomicAdd(&drow[lane * 4 + 0], w * v.x);
        atomicAdd(&drow[lane * 4 + 1], w * v.y);
        atomicAdd(&drow[lane * 4 + 2], w * v.z);
        atomicAdd(&drow[lane * 4 + 3], w * v.w);
    }
}

// ========== K7: GEMM2  out = ((ha + d2*h)*g) @ W2 + c⊗(s̄@W2) + b2 ==========
__global__ __launch_bounds__(256) void k_gemm2(
    const float* __restrict__ h, const float* __restrict__ ha,
    const float* __restrict__ musum, const float* __restrict__ sqsum,
    const float* __restrict__ gamma, const float* __restrict__ beta,
    const float* __restrict__ W2, const unsigned short* __restrict__ W2T,
    const float* __restrict__ b2, const float* __restrict__ deg,
    const float* __restrict__ cvec, float* __restrict__ out) {
    __shared__ __align__(16) unsigned short As[64][40];
    __shared__ __align__(16) unsigned short Bs[64][40];
    __shared__ __align__(16) float gvec[HID];
    __shared__ __align__(16) float svec[HID];
    __shared__ __align__(16) float tvec[OUTC];
    int z = blockIdx.z;
    const float* hz = h + (size_t)z * BATCH * HID;
    const float* haz = ha + (size_t)z * BATCH * HID;
    const float* dgz = deg + z * BATCH;
    const float* cvz = cvec + z * BATCH;
    float* oz = out + (size_t)z * BATCH * OUTC;
    int m0 = blockIdx.y * 64, n0 = blockIdx.x * 64;
    int t = threadIdx.x;

    // BN finalize: g, s̄
#pragma unroll
    for (int c = t; c < HID; c += 256) {
        float mu = musum[z * HID + c] * (1.0f / BATCH);
        float ex2 = sqsum[z * HID + c] * (1.0f / BATCH);
        float var = ex2 - mu * mu;
        float g = rsqrtf(var + BN_EPS) * gamma[c];
        gvec[c] = g;
        svec[c] = beta[c] - mu * g;
    }
    __syncthreads();
    // tvec = s̄ @ W2   (col = t)
    {
        float tc = 0.0f;
#pragma unroll 4
        for (int k = 0; k < HID; ++k) tc += svec[k] * W2[(size_t)k * OUTC + t];
        tvec[t] = tc;
    }
    __syncthreads();

    int ar = t >> 2, aq = t & 3;
    const float* haptr = haz + (size_t)(m0 + ar) * HID + aq * 8;
    const float* hptr  = hz  + (size_t)(m0 + ar) * HID + aq * 8;
    float d2row = 1.0f / (dgz[m0 + ar] + 1.0f);
    const unsigned short* bptr = W2T + (size_t)(n0 + ar) * HID + aq * 8;

    int lane = t & 63, wave = t >> 6;
    int wm = (wave & 1) * 32, wn = (wave >> 1) * 32;
    int ml = lane & 15, quad = lane >> 4, q8 = quad * 8;

    f32x4 acc[2][2] = {};
    for (int k0 = 0; k0 < HID; k0 += 32) {
        float4 u0 = *(const float4*)(haptr + k0);
        float4 u1 = *(const float4*)(haptr + k0 + 4);
        float4 v0 = *(const float4*)(hptr + k0);
        float4 v1 = *(const float4*)(hptr + k0 + 4);
        float4 g0 = *(const float4*)(gvec + k0 + aq * 8);
        float4 g1 = *(const float4*)(gvec + k0 + aq * 8 + 4);
        float4 a0 = make_float4((u0.x + d2row * v0.x) * g0.x, (u0.y + d2row * v0.y) * g0.y,
                                (u0.z + d2row * v0.z) * g0.z, (u0.w + d2row * v0.w) * g0.w);
        float4 a1 = make_float4((u1.x + d2row * v1.x) * g1.x, (u1.y + d2row * v1.y) * g1.y,
                                (u1.z + d2row * v1.z) * g1.z, (u1.w + d2row * v1.w) * g1.w);
        uint4 bv = *(const uint4*)(bptr + k0);
        *(uint4*)&As[ar][aq * 8] = pack8(a0, a1);
        *(uint4*)&Bs[ar][aq * 8] = bv;
        __syncthreads();
        bf16x8 af[2], bfr[2];
#pragma unroll
        for (int mi = 0; mi < 2; ++mi) af[mi]  = *(const bf16x8*)&As[wm + mi * 16 + ml][q8];
#pragma unroll
        for (int ni = 0; ni < 2; ++ni) bfr[ni] = *(const bf16x8*)&Bs[wn + ni * 16 + ml][q8];
#pragma unroll
        for (int mi = 0; mi < 2; ++mi)
#pragma unroll
            for (int ni = 0; ni < 2; ++ni)
                acc[mi][ni] = __builtin_amdgcn_mfma_f32_16x16x32_bf16(af[mi], bfr[ni], acc[mi][ni], 0, 0, 0);
        __syncthreads();
    }
#pragma unroll
    for (int mi = 0; mi < 2; ++mi)
#pragma unroll
        for (int r = 0; r < 4; ++r) {
            int row = m0 + wm + mi * 16 + quad * 4 + r;
            float cv = cvz[row];
#pragma unroll
            for (int ni = 0; ni < 2; ++ni) {
                int col = n0 + wn + ni * 16 + ml;
                oz[(size_t)row * OUTC + col] = acc[mi][ni][r] + cv * tvec[col] + b2[col];
            }
        }
}

// ---------------- launch ----------------
extern "C" void kernel_launch(void* const* d_in, const int* in_sizes, int n_in,
                              void* d_out, int out_size, void* d_ws, size_t ws_size,
                              hipStream_t stream) {
    const float* features    = (const float*)d_in[0];
    const float* W1          = (const float*)d_in[1];
    const float* b1          = (const float*)d_in[2];
    const float* W2          = (const float*)d_in[3];
    const float* b2          = (const float*)d_in[4];
    const float* gamma       = (const float*)d_in[5];
    const float* beta        = (const float*)d_in[6];
    const int*   edge_index  = (const int*)d_in[7];
    const int*   batch_nodes = (const int*)d_in[8];
    float* out = (float*)d_out;

    char* p = (char*)d_ws;
    size_t cur = 0;
    auto alloc = [&](size_t bytes) {
        void* r = p + cur;
        cur = (cur + bytes + 255) & ~(size_t)255;
        return r;
    };
    int*   inv    = (int*)  alloc(NNODES * sizeof(int));
    int*   appear = (int*)  alloc(RNUM * BATCH * sizeof(int));
    int*   kcount = (int*)  alloc(RNUM * sizeof(int));
    float* deg    = (float*)alloc(RNUM * BATCH * sizeof(float));
    float* cvec   = (float*)alloc(RNUM * BATCH * sizeof(float));
    float* musum  = (float*)alloc(RNUM * HID * sizeof(float));
    float* sqsum  = (float*)alloc(RNUM * HID * sizeof(float));
    unsigned short* W1T = (unsigned short*)alloc((size_t)HID * INP * sizeof(unsigned short));
    unsigned short* W2T = (unsigned short*)alloc((size_t)OUTC * HID * sizeof(unsigned short));
    int2*  edges  = (int2*) alloc((size_t)RNUM * ENUM * sizeof(int2));
    float* xa     = (float*)alloc((size_t)RNUM * BATCH * INP * sizeof(float));
    float* ha     = (float*)alloc((size_t)RNUM * BATCH * HID * sizeof(float));
    float* h      = (float*)alloc((size_t)RNUM * BATCH * HID * sizeof(float));
    (void)ws_size; (void)in_sizes; (void)n_in; (void)out_size;

    k_prep<<<1024, 256, 0, stream>>>(W1, W2, batch_nodes, W1T, W2T, inv, appear,
                                     kcount, musum, sqsum, xa, ha);
    k_mask<<<dim3(512, 1, RNUM), 256, 0, stream>>>(edge_index, inv, appear, edges, kcount);
    k_scanDeg<<<RNUM, 1024, 0, stream>>>(appear, edges, kcount, deg, cvec);
    k_aggx<<<dim3(128, 1, RNUM), 256, 0, stream>>>(edges, kcount, deg, features,
                                                   batch_nodes, xa);
    k_gemm1<<<dim3(HID / 64, BATCH / 64, RNUM), 256, 0, stream>>>(
        features, batch_nodes, xa, W1T, b1, deg, h, musum, sqsum);
    k_aggh<<<dim3(256, 1, RNUM), 256, 0, stream>>>(edges, kcount, deg, h, ha);
    k_gemm2<<<dim3(OUTC / 64, BATCH / 64, RNUM), 256, 0, stream>>>(
        h, ha, musum, sqsum, gamma, beta, W2, W2T, b2, deg, cvec, out);
}